// Round 1
// baseline (399.743 us; speedup 1.0000x reference)
//
#include <hip/hip_runtime.h>
#include <math.h>

// Problem constants (SelectiveSSM)
#define BATCH   2
#define SEQLEN  512
#define DI      4096      // d_inner
#define DS      16        // d_state
#define RDT     128       // dt_rank
#define RTOT    160       // dt_rank + 2*d_state
#define BL      1024      // BATCH*SEQLEN rows

#define KSPLIT  16        // GEMM1 k-split: 4096/16 = 256 per block

// ---------------------------------------------------------------------------
// Kernel 1: xp_part[ks][row][r] = sum over k-slice of x[row,k]*W[r,k]
// grid (16 row-blocks, 16 k-splits), block 256.
// Tile: 64 rows x 160 cols. LDS: xs[64][65] + wt[160][65] = 58.2 KB.
// Thread (ti=tid>>4, tj=tid&15): rows {4ti..4ti+3}, cols {tj+16c, c=0..9}.
// ---------------------------------------------------------------------------
__global__ __launch_bounds__(256) void gemm_xp(const float* __restrict__ x,
                                               const float* __restrict__ W,
                                               float* __restrict__ part) {
  __shared__ float xs[64][65];
  __shared__ float wt[160][65];
  const int tid = threadIdx.x;
  const int row0 = blockIdx.x * 64;
  const int k0 = blockIdx.y * (DI / KSPLIT);   // 256-wide K slice
  const int ti = tid >> 4;
  const int tj = tid & 15;

  float acc[4][10];
#pragma unroll
  for (int r = 0; r < 4; ++r)
#pragma unroll
    for (int c = 0; c < 10; ++c) acc[r][c] = 0.f;

  for (int kc = 0; kc < 4; ++kc) {             // 4 chunks of 64
    const int kb = k0 + kc * 64;
    for (int idx = tid; idx < 64 * 64; idx += 256) {
      const int kk = idx & 63, r = idx >> 6;
      xs[r][kk] = x[(row0 + r) * DI + kb + kk];
    }
    for (int idx = tid; idx < 160 * 64; idx += 256) {
      const int kk = idx & 63, c = idx >> 6;
      wt[c][kk] = W[c * DI + kb + kk];
    }
    __syncthreads();
#pragma unroll 4
    for (int kk = 0; kk < 64; ++kk) {
      const float a0 = xs[4 * ti + 0][kk];
      const float a1 = xs[4 * ti + 1][kk];
      const float a2 = xs[4 * ti + 2][kk];
      const float a3 = xs[4 * ti + 3][kk];
#pragma unroll
      for (int c = 0; c < 10; ++c) {
        const float w = wt[tj + 16 * c][kk];
        acc[0][c] += a0 * w;
        acc[1][c] += a1 * w;
        acc[2][c] += a2 * w;
        acc[3][c] += a3 * w;
      }
    }
    __syncthreads();
  }

  float* p = part + blockIdx.y * (BL * RTOT);
#pragma unroll
  for (int r = 0; r < 4; ++r)
#pragma unroll
    for (int c = 0; c < 10; ++c)
      p[(row0 + 4 * ti + r) * RTOT + tj + 16 * c] = acc[r][c];
}

// ---------------------------------------------------------------------------
// Kernel 1b: xp[o] = sum_s part[s][o]   (163840 outputs, grid 640)
// ---------------------------------------------------------------------------
__global__ __launch_bounds__(256) void reduce_xp(const float* __restrict__ part,
                                                 float* __restrict__ xp) {
  const int o = blockIdx.x * 256 + threadIdx.x;
  float s = 0.f;
#pragma unroll
  for (int k = 0; k < KSPLIT; ++k) s += part[k * (BL * RTOT) + o];
  xp[o] = s;
}

// ---------------------------------------------------------------------------
// Kernel 2: dtbuf[row][d] = softplus( sum_r xp[row][r]*dtw[d][r] + dtb[d] )
// grid (16 row-blocks, 32 col-blocks), block 256. Tile 64 rows x 128 cols.
// LDS: as_[64][65] + wt2[128][65] = 50 KB.
// ---------------------------------------------------------------------------
__global__ __launch_bounds__(256) void gemm_dt(const float* __restrict__ xp,
                                               const float* __restrict__ dtw,
                                               const float* __restrict__ dtb,
                                               float* __restrict__ dtbuf) {
  __shared__ float as_[64][65];
  __shared__ float wt2[128][65];
  const int tid = threadIdx.x;
  const int row0 = blockIdx.x * 64;
  const int d0 = blockIdx.y * 128;
  const int ti = tid >> 4;
  const int tj = tid & 15;

  float acc[4][8];
#pragma unroll
  for (int r = 0; r < 4; ++r)
#pragma unroll
    for (int c = 0; c < 8; ++c) acc[r][c] = 0.f;

  for (int kc = 0; kc < 2; ++kc) {             // K=128 in 2 chunks of 64
    const int kb = kc * 64;
    for (int idx = tid; idx < 64 * 64; idx += 256) {
      const int kk = idx & 63, r = idx >> 6;
      as_[r][kk] = xp[(row0 + r) * RTOT + kb + kk];   // dt_in = xp[:, 0:128]
    }
    for (int idx = tid; idx < 128 * 64; idx += 256) {
      const int kk = idx & 63, c = idx >> 6;
      wt2[c][kk] = dtw[(d0 + c) * RDT + kb + kk];
    }
    __syncthreads();
#pragma unroll 4
    for (int kk = 0; kk < 64; ++kk) {
      const float a0 = as_[4 * ti + 0][kk];
      const float a1 = as_[4 * ti + 1][kk];
      const float a2 = as_[4 * ti + 2][kk];
      const float a3 = as_[4 * ti + 3][kk];
#pragma unroll
      for (int c = 0; c < 8; ++c) {
        const float w = wt2[tj + 16 * c][kk];
        acc[0][c] += a0 * w;
        acc[1][c] += a1 * w;
        acc[2][c] += a2 * w;
        acc[3][c] += a3 * w;
      }
    }
    __syncthreads();
  }

#pragma unroll
  for (int r = 0; r < 4; ++r)
#pragma unroll
    for (int c = 0; c < 8; ++c) {
      const int col = d0 + tj + 16 * c;
      const float z = acc[r][c] + dtb[col];
      const float sp = (z > 20.f) ? z : log1pf(__expf(z));
      dtbuf[(row0 + 4 * ti + r) * DI + col] = sp;
    }
}

// ---------------------------------------------------------------------------
// Kernel 3: selective scan. 16 lanes per channel (one state n per lane).
// grid 512 blocks x 256 threads: block = 16 channels of one batch.
// tid: n = tid&15 (state), dc = tid>>4 (channel within block).
// y reduction via shfl_xor within 16-lane groups.
// ---------------------------------------------------------------------------
__global__ __launch_bounds__(256) void scan_kernel(const float* __restrict__ x,
                                                   const float* __restrict__ A_log,
                                                   const float* __restrict__ Dvec,
                                                   const float* __restrict__ xp,
                                                   const float* __restrict__ dtbuf,
                                                   float* __restrict__ out) {
  const int bid = blockIdx.x;         // 0..511
  const int b = bid >> 8;             // batch
  const int d0 = (bid & 255) * 16;    // 16 channels per block
  const int tid = threadIdx.x;
  const int n = tid & 15;
  const int dc = tid >> 4;
  const int d = d0 + dc;

  const float A = -expf(A_log[d * DS + n]);
  const float Dd = Dvec[d];

  float h = 0.f;
  const int rowbase = b * SEQLEN;
  for (int t = 0; t < SEQLEN; ++t) {
    const int row = rowbase + t;
    const float dt = dtbuf[row * DI + d];
    const float xv = x[row * DI + d];
    const float Bv = xp[row * RTOT + RDT + n];
    const float Cv = xp[row * RTOT + RDT + DS + n];
    const float dA = __expf(dt * A);
    h = dA * h + (dt * xv) * Bv;
    float p = h * Cv;
    p += __shfl_xor(p, 1);
    p += __shfl_xor(p, 2);
    p += __shfl_xor(p, 4);
    p += __shfl_xor(p, 8);
    if (n == 0) out[row * DI + d] = p + Dd * xv;
  }
}

// ---------------------------------------------------------------------------
extern "C" void kernel_launch(void* const* d_in, const int* in_sizes, int n_in,
                              void* d_out, int out_size, void* d_ws, size_t ws_size,
                              hipStream_t stream) {
  const float* x     = (const float*)d_in[0];  // (2,512,4096)
  const float* A_log = (const float*)d_in[1];  // (4096,16)
  const float* Dv    = (const float*)d_in[2];  // (4096,)
  const float* W     = (const float*)d_in[3];  // (160,4096)
  const float* dtw   = (const float*)d_in[4];  // (4096,128)
  const float* dtb   = (const float*)d_in[5];  // (4096,)
  float* out = (float*)d_out;

  char* ws = (char*)d_ws;
  float* dtbuf = (float*)ws;                                    // 16,777,216 B
  float* xp    = (float*)(ws + (size_t)BL * DI * 4);            //    655,360 B
  float* part  = (float*)(ws + (size_t)BL * DI * 4 + (size_t)BL * RTOT * 4);
  // part: KSPLIT * 1024 * 160 * 4 = 10,485,760 B ; total ~27.9 MB

  gemm_xp<<<dim3(16, KSPLIT), 256, 0, stream>>>(x, W, part);
  reduce_xp<<<dim3(640), 256, 0, stream>>>(part, xp);
  gemm_dt<<<dim3(16, 32), 256, 0, stream>>>(xp, dtw, dtb, dtbuf);
  scan_kernel<<<dim3(512), 256, 0, stream>>>(x, A_log, Dv, xp, dtbuf, out);
}

// Round 2
// 215.506 us; speedup vs baseline: 1.8549x; 1.8549x over previous
//
#include <hip/hip_runtime.h>
#include <math.h>

// Problem constants (SelectiveSSM)
#define BATCH   2
#define SEQLEN  512
#define DI      4096      // d_inner
#define DS      16        // d_state
#define RDT     128       // dt_rank
#define RTOT    160       // dt_rank + 2*d_state
#define BL      1024      // BATCH*SEQLEN rows

#define KSPLIT  16        // GEMM1 k-split: 4096/16 = 256 per block

// ---------------------------------------------------------------------------
// Kernel 1: xp_part[ks][row][r] = sum over k-slice of x[row,k]*W[r,k]
// ---------------------------------------------------------------------------
__global__ __launch_bounds__(256) void gemm_xp(const float* __restrict__ x,
                                               const float* __restrict__ W,
                                               float* __restrict__ part) {
  __shared__ float xs[64][65];
  __shared__ float wt[160][65];
  const int tid = threadIdx.x;
  const int row0 = blockIdx.x * 64;
  const int k0 = blockIdx.y * (DI / KSPLIT);   // 256-wide K slice
  const int ti = tid >> 4;
  const int tj = tid & 15;

  float acc[4][10];
#pragma unroll
  for (int r = 0; r < 4; ++r)
#pragma unroll
    for (int c = 0; c < 10; ++c) acc[r][c] = 0.f;

  for (int kc = 0; kc < 4; ++kc) {             // 4 chunks of 64
    const int kb = k0 + kc * 64;
    for (int idx = tid; idx < 64 * 64; idx += 256) {
      const int kk = idx & 63, r = idx >> 6;
      xs[r][kk] = x[(row0 + r) * DI + kb + kk];
    }
    for (int idx = tid; idx < 160 * 64; idx += 256) {
      const int kk = idx & 63, c = idx >> 6;
      wt[c][kk] = W[c * DI + kb + kk];
    }
    __syncthreads();
#pragma unroll 4
    for (int kk = 0; kk < 64; ++kk) {
      const float a0 = xs[4 * ti + 0][kk];
      const float a1 = xs[4 * ti + 1][kk];
      const float a2 = xs[4 * ti + 2][kk];
      const float a3 = xs[4 * ti + 3][kk];
#pragma unroll
      for (int c = 0; c < 10; ++c) {
        const float w = wt[tj + 16 * c][kk];
        acc[0][c] += a0 * w;
        acc[1][c] += a1 * w;
        acc[2][c] += a2 * w;
        acc[3][c] += a3 * w;
      }
    }
    __syncthreads();
  }

  float* p = part + blockIdx.y * (BL * RTOT);
#pragma unroll
  for (int r = 0; r < 4; ++r)
#pragma unroll
    for (int c = 0; c < 10; ++c)
      p[(row0 + 4 * ti + r) * RTOT + tj + 16 * c] = acc[r][c];
}

// ---------------------------------------------------------------------------
// Kernel 1b: xp[o] = sum_s part[s][o]
// ---------------------------------------------------------------------------
__global__ __launch_bounds__(256) void reduce_xp(const float* __restrict__ part,
                                                 float* __restrict__ xp) {
  const int o = blockIdx.x * 256 + threadIdx.x;
  float s = 0.f;
#pragma unroll
  for (int k = 0; k < KSPLIT; ++k) s += part[k * (BL * RTOT) + o];
  xp[o] = s;
}

// ---------------------------------------------------------------------------
// Kernel 2: dtbuf[row][d] = softplus( sum_r xp[row][r]*dtw[d][r] + dtb[d] )
// ---------------------------------------------------------------------------
__global__ __launch_bounds__(256) void gemm_dt(const float* __restrict__ xp,
                                               const float* __restrict__ dtw,
                                               const float* __restrict__ dtb,
                                               float* __restrict__ dtbuf) {
  __shared__ float as_[64][65];
  __shared__ float wt2[128][65];
  const int tid = threadIdx.x;
  const int row0 = blockIdx.x * 64;
  const int d0 = blockIdx.y * 128;
  const int ti = tid >> 4;
  const int tj = tid & 15;

  float acc[4][8];
#pragma unroll
  for (int r = 0; r < 4; ++r)
#pragma unroll
    for (int c = 0; c < 8; ++c) acc[r][c] = 0.f;

  for (int kc = 0; kc < 2; ++kc) {             // K=128 in 2 chunks of 64
    const int kb = kc * 64;
    for (int idx = tid; idx < 64 * 64; idx += 256) {
      const int kk = idx & 63, r = idx >> 6;
      as_[r][kk] = xp[(row0 + r) * RTOT + kb + kk];   // dt_in = xp[:, 0:128]
    }
    for (int idx = tid; idx < 128 * 64; idx += 256) {
      const int kk = idx & 63, c = idx >> 6;
      wt2[c][kk] = dtw[(d0 + c) * RDT + kb + kk];
    }
    __syncthreads();
#pragma unroll 4
    for (int kk = 0; kk < 64; ++kk) {
      const float a0 = as_[4 * ti + 0][kk];
      const float a1 = as_[4 * ti + 1][kk];
      const float a2 = as_[4 * ti + 2][kk];
      const float a3 = as_[4 * ti + 3][kk];
#pragma unroll
      for (int c = 0; c < 8; ++c) {
        const float w = wt2[tj + 16 * c][kk];
        acc[0][c] += a0 * w;
        acc[1][c] += a1 * w;
        acc[2][c] += a2 * w;
        acc[3][c] += a3 * w;
      }
    }
    __syncthreads();
  }

#pragma unroll
  for (int r = 0; r < 4; ++r)
#pragma unroll
    for (int c = 0; c < 8; ++c) {
      const int col = d0 + tj + 16 * c;
      const float z = acc[r][c] + dtb[col];
      const float sp = (z > 20.f) ? z : log1pf(__expf(z));
      dtbuf[(row0 + 4 * ti + r) * DI + col] = sp;
    }
}

// ---------------------------------------------------------------------------
// 16-lane (DPP row) sum reduction on the VALU pipe — no DS ops.
// After row_shr 1,2,4,8 with bound_ctrl (OOB -> 0), lane 15 of each
// 16-lane row holds the full row sum.
// ---------------------------------------------------------------------------
__device__ __forceinline__ float row16_reduce_add(float p) {
  p += __int_as_float(__builtin_amdgcn_update_dpp(
      0, __float_as_int(p), 0x111, 0xf, 0xf, true));  // row_shr:1
  p += __int_as_float(__builtin_amdgcn_update_dpp(
      0, __float_as_int(p), 0x112, 0xf, 0xf, true));  // row_shr:2
  p += __int_as_float(__builtin_amdgcn_update_dpp(
      0, __float_as_int(p), 0x114, 0xf, 0xf, true));  // row_shr:4
  p += __int_as_float(__builtin_amdgcn_update_dpp(
      0, __float_as_int(p), 0x118, 0xf, 0xf, true));  // row_shr:8
  return p;
}

// ---------------------------------------------------------------------------
// Kernel 3: selective scan, LDS-staged chunks.
// Block = 16 channels of one batch (512 blocks x 256 threads).
// lane: n = tid&15 (state, = DPP row lane), dc = tid>>4 (channel 0..15).
// Chunks of TC=64 timesteps staged in LDS:
//   dxS[t][dc] = (dt, x)   bcS[t][n] = (B, C)   yS[t][dc] = output
// Global loads are float4-coalesced, register-prefetched one chunk ahead.
// y is buffered in LDS and bulk-stored as coalesced float4.
// ---------------------------------------------------------------------------
#define TC  64
#define NCH (SEQLEN / TC)

__global__ __launch_bounds__(256) void scan_kernel(const float* __restrict__ x,
                                                   const float* __restrict__ A_log,
                                                   const float* __restrict__ Dvec,
                                                   const float* __restrict__ xp,
                                                   const float* __restrict__ dtbuf,
                                                   float* __restrict__ out) {
  __shared__ float2 dxS[TC][16];
  __shared__ float2 bcS[TC][16];
  __shared__ float  yS[TC][16];

  const int bid = blockIdx.x;         // 0..511
  const int b = bid >> 8;             // batch
  const int d0 = (bid & 255) * 16;    // 16 channels per block
  const int tid = threadIdx.x;
  const int n = tid & 15;
  const int dc = tid >> 4;
  const int d = d0 + dc;

  const float A = -expf(A_log[d * DS + n]);
  const float Dd = Dvec[d];

  // loader mapping: thread tid -> row lt (0..63), 4-float slice lf
  const int lt = tid >> 2;
  const int lf = (tid & 3) * 4;
  const int rowbase = b * SEQLEN;

  float4 rdt, rx, rB, rC;
  {
    const int row = rowbase + lt;
    rdt = *(const float4*)&dtbuf[row * DI + d0 + lf];
    rx  = *(const float4*)&x[row * DI + d0 + lf];
    rB  = *(const float4*)&xp[row * RTOT + RDT + lf];
    rC  = *(const float4*)&xp[row * RTOT + RDT + DS + lf];
  }

  float h = 0.f;

  for (int c = 0; c < NCH; ++c) {
    if (c > 0) __syncthreads();   // prev compute done: tile reads + yS writes complete

    // regs -> LDS tiles (two float4 stores per array; 16B aligned)
    {
      float4 w0 = make_float4(rdt.x, rx.x, rdt.y, rx.y);
      float4 w1 = make_float4(rdt.z, rx.z, rdt.w, rx.w);
      *(float4*)&dxS[lt][lf]     = w0;
      *(float4*)&dxS[lt][lf + 2] = w1;
      float4 v0 = make_float4(rB.x, rC.x, rB.y, rC.y);
      float4 v1 = make_float4(rB.z, rC.z, rB.w, rC.w);
      *(float4*)&bcS[lt][lf]     = v0;
      *(float4*)&bcS[lt][lf + 2] = v1;
    }

    // store previous chunk's y (safe: after barrier, different LDS region)
    if (c > 0) {
      const int prow = rowbase + (c - 1) * TC + lt;
      float4 yv = *(const float4*)&yS[lt][lf];
      *(float4*)&out[prow * DI + d0 + lf] = yv;
    }

    __syncthreads();              // tiles ready; yS reads done

    // prefetch next chunk into registers (latency overlapped with compute)
    if (c < NCH - 1) {
      const int row = rowbase + (c + 1) * TC + lt;
      rdt = *(const float4*)&dtbuf[row * DI + d0 + lf];
      rx  = *(const float4*)&x[row * DI + d0 + lf];
      rB  = *(const float4*)&xp[row * RTOT + RDT + lf];
      rC  = *(const float4*)&xp[row * RTOT + RDT + DS + lf];
    }

    // 64 sequential steps from LDS
#pragma unroll 8
    for (int t = 0; t < TC; ++t) {
      const float2 dx = dxS[t][dc];
      const float2 bc = bcS[t][n];
      const float dt = dx.x, xv = dx.y;
      const float dA = __expf(dt * A);
      h = fmaf(dA, h, dt * xv * bc.x);
      float p = row16_reduce_add(h * bc.y);
      if (n == 15) yS[t][dc] = fmaf(Dd, xv, p);
    }
  }

  __syncthreads();
  {
    const int prow = rowbase + (NCH - 1) * TC + lt;
    float4 yv = *(const float4*)&yS[lt][lf];
    *(float4*)&out[prow * DI + d0 + lf] = yv;
  }
}

// ---------------------------------------------------------------------------
extern "C" void kernel_launch(void* const* d_in, const int* in_sizes, int n_in,
                              void* d_out, int out_size, void* d_ws, size_t ws_size,
                              hipStream_t stream) {
  const float* x     = (const float*)d_in[0];  // (2,512,4096)
  const float* A_log = (const float*)d_in[1];  // (4096,16)
  const float* Dv    = (const float*)d_in[2];  // (4096,)
  const float* W     = (const float*)d_in[3];  // (160,4096)
  const float* dtw   = (const float*)d_in[4];  // (4096,128)
  const float* dtb   = (const float*)d_in[5];  // (4096,)
  float* out = (float*)d_out;

  char* ws = (char*)d_ws;
  float* dtbuf = (float*)ws;                                    // 16,777,216 B
  float* xp    = (float*)(ws + (size_t)BL * DI * 4);            //    655,360 B
  float* part  = (float*)(ws + (size_t)BL * DI * 4 + (size_t)BL * RTOT * 4);
  // part: KSPLIT * 1024 * 160 * 4 = 10,485,760 B ; total ~27.9 MB

  gemm_xp<<<dim3(16, KSPLIT), 256, 0, stream>>>(x, W, part);
  reduce_xp<<<dim3(640), 256, 0, stream>>>(part, xp);
  gemm_dt<<<dim3(16, 32), 256, 0, stream>>>(xp, dtw, dtb, dtbuf);
  scan_kernel<<<dim3(512), 256, 0, stream>>>(x, A_log, Dv, xp, dtbuf, out);
}

// Round 3
// 165.702 us; speedup vs baseline: 2.4124x; 1.3006x over previous
//
#include <hip/hip_runtime.h>
#include <math.h>

// Problem constants (SelectiveSSM)
#define BATCH   2
#define SEQLEN  512
#define DI      4096      // d_inner
#define DS      16        // d_state
#define RDT     128       // dt_rank
#define RTOT    160       // dt_rank + 2*d_state
#define BL      1024      // BATCH*SEQLEN rows

#define KSPLIT  16        // GEMM1 k-split: 4096/16 = 256 per block

typedef __bf16 bf16;
typedef bf16  bf16x8 __attribute__((ext_vector_type(8)));
typedef bf16  bf16x4 __attribute__((ext_vector_type(4)));
typedef float f32x4  __attribute__((ext_vector_type(4)));

// ---------------------------------------------------------------------------
// Cast fp32 -> bf16, vectorized (n4 = element count / 4)
// ---------------------------------------------------------------------------
__global__ __launch_bounds__(256) void cast_bf16(const float* __restrict__ src,
                                                 bf16* __restrict__ dst, int n4) {
  const int i = blockIdx.x * 256 + threadIdx.x;
  if (i < n4) {
    float4 v = ((const float4*)src)[i];
    bf16x4 o;
    o[0] = (bf16)v.x; o[1] = (bf16)v.y; o[2] = (bf16)v.z; o[3] = (bf16)v.w;
    *(bf16x4*)(dst + 4 * (size_t)i) = o;
  }
}

// ---------------------------------------------------------------------------
// GEMM1 (MFMA, no LDS): part[ks][row][r] = sum_{k in slice} x[row,k]*W[r,k]
// grid (16 M-tiles, 16 k-splits) x 256. Wave w: rows row0+16w..+15.
// 16x16x32 bf16 MFMA. A: x fp32 loaded + cvt in-reg. B: pre-cast Wb (L2-hot).
// Fragment pattern: lane = m + 16q reads row m, k-offset 8q -> 16 rows x 64B
// lines, fully coalesced dwordx4, no LDS staging needed.
// ---------------------------------------------------------------------------
__global__ __launch_bounds__(256) void gemm_xp_mfma(const float* __restrict__ x,
                                                    const bf16* __restrict__ Wb,
                                                    float* __restrict__ part) {
  const int tid = threadIdx.x;
  const int w = tid >> 6;
  const int lane = tid & 63;
  const int m = lane & 15;
  const int q = lane >> 4;
  const int row0 = blockIdx.x * 64 + 16 * w;
  const int k0 = blockIdx.y * (DI / KSPLIT);   // 256-wide K slice

  f32x4 acc[10] = {};

  const float* ap = x + (size_t)(row0 + m) * DI + k0 + 8 * q;
  const bf16*  bp = Wb + (size_t)m * DI + k0 + 8 * q;

#pragma unroll 2
  for (int kk = 0; kk < DI / KSPLIT; kk += 32) {
    float4 a0 = *(const float4*)(ap + kk);
    float4 a1 = *(const float4*)(ap + kk + 4);
    bf16x8 af;
    af[0] = (bf16)a0.x; af[1] = (bf16)a0.y; af[2] = (bf16)a0.z; af[3] = (bf16)a0.w;
    af[4] = (bf16)a1.x; af[5] = (bf16)a1.y; af[6] = (bf16)a1.z; af[7] = (bf16)a1.w;
#pragma unroll
    for (int nt = 0; nt < 10; ++nt) {
      bf16x8 bf = *(const bf16x8*)(bp + (size_t)nt * 16 * DI + kk);
      acc[nt] = __builtin_amdgcn_mfma_f32_16x16x32_bf16(af, bf, acc[nt], 0, 0, 0);
    }
  }

  // C/D layout: col = lane&15 (=m), row = q*4 + reg
  float* p = part + (size_t)blockIdx.y * (BL * RTOT);
#pragma unroll
  for (int nt = 0; nt < 10; ++nt)
#pragma unroll
    for (int r = 0; r < 4; ++r)
      p[(size_t)(row0 + 4 * q + r) * RTOT + nt * 16 + m] = acc[nt][r];
}

// ---------------------------------------------------------------------------
// Reduce k-splits; emit xp fp32 (scan reads B,C) + dt_in bf16 (GEMM2 A).
// ---------------------------------------------------------------------------
__global__ __launch_bounds__(256) void reduce_xp(const float* __restrict__ part,
                                                 float* __restrict__ xp,
                                                 bf16* __restrict__ dtinb) {
  const int o = blockIdx.x * 256 + threadIdx.x;   // 163840 outputs
  float s = 0.f;
#pragma unroll
  for (int k = 0; k < KSPLIT; ++k) s += part[(size_t)k * (BL * RTOT) + o];
  xp[o] = s;
  const int row = o / RTOT;
  const int col = o - row * RTOT;
  if (col < RDT) dtinb[row * RDT + col] = (bf16)s;
}

// ---------------------------------------------------------------------------
// GEMM2 (MFMA, no LDS): dtbuf[row][d] = softplus(dt_in[row]·dtw[d] + dtb[d])
// grid (16 M-tiles, 32 N-tiles) x 256. K=128 = 4 ksteps. B tile (32KB) L1-hot.
// ---------------------------------------------------------------------------
__global__ __launch_bounds__(256) void gemm_dt_mfma(const bf16* __restrict__ Ab,
                                                    const bf16* __restrict__ Bb,
                                                    const float* __restrict__ dtb,
                                                    float* __restrict__ dtbuf) {
  const int tid = threadIdx.x;
  const int w = tid >> 6;
  const int lane = tid & 63;
  const int m = lane & 15;
  const int q = lane >> 4;
  const int row0 = blockIdx.x * 64 + 16 * w;
  const int n0 = blockIdx.y * 128;

  f32x4 acc[8] = {};

  const bf16* apb = Ab + (size_t)(row0 + m) * RDT + 8 * q;
  const bf16* bpb = Bb + (size_t)(n0 + m) * RDT + 8 * q;

#pragma unroll
  for (int kk = 0; kk < RDT; kk += 32) {
    bf16x8 af = *(const bf16x8*)(apb + kk);
#pragma unroll
    for (int nt = 0; nt < 8; ++nt) {
      bf16x8 bf = *(const bf16x8*)(bpb + (size_t)nt * 16 * RDT + kk);
      acc[nt] = __builtin_amdgcn_mfma_f32_16x16x32_bf16(af, bf, acc[nt], 0, 0, 0);
    }
  }

#pragma unroll
  for (int nt = 0; nt < 8; ++nt) {
    const int col = n0 + nt * 16 + m;
    const float bias = dtb[col];
#pragma unroll
    for (int r = 0; r < 4; ++r) {
      const float z = acc[nt][r] + bias;
      const float sp = (z > 20.f) ? z : __logf(1.f + __expf(z));
      dtbuf[(size_t)(row0 + 4 * q + r) * DI + col] = sp;
    }
  }
}

// ---------------------------------------------------------------------------
// 16-lane (DPP row) sum reduction on the VALU pipe — no DS ops.
// ---------------------------------------------------------------------------
__device__ __forceinline__ float row16_reduce_add(float p) {
  p += __int_as_float(__builtin_amdgcn_update_dpp(
      0, __float_as_int(p), 0x111, 0xf, 0xf, true));  // row_shr:1
  p += __int_as_float(__builtin_amdgcn_update_dpp(
      0, __float_as_int(p), 0x112, 0xf, 0xf, true));  // row_shr:2
  p += __int_as_float(__builtin_amdgcn_update_dpp(
      0, __float_as_int(p), 0x114, 0xf, 0xf, true));  // row_shr:4
  p += __int_as_float(__builtin_amdgcn_update_dpp(
      0, __float_as_int(p), 0x118, 0xf, 0xf, true));  // row_shr:8
  return p;
}

// ---------------------------------------------------------------------------
// Kernel 3: selective scan. Transposed LDS tiles: [ch][t] so one b128 read
// fetches TWO timesteps (halves LDS ops vs round 2). Inner dim padded to 66
// (+2) so writes are <=2-way (free) and reads conflict-free.
// ---------------------------------------------------------------------------
#define TC  64
#define TCP 66
#define NCH (SEQLEN / TC)

__global__ __launch_bounds__(256) void scan_kernel(const float* __restrict__ x,
                                                   const float* __restrict__ A_log,
                                                   const float* __restrict__ Dvec,
                                                   const float* __restrict__ xp,
                                                   const float* __restrict__ dtbuf,
                                                   float* __restrict__ out) {
  __shared__ __align__(16) float2 dxS[16][TCP];  // [dc][t] = (dt, x)
  __shared__ __align__(16) float2 bcS[16][TCP];  // [n][t]  = (B, C)
  __shared__ __align__(16) float  yS[TC][16];

  const int bid = blockIdx.x;         // 0..511
  const int b = bid >> 8;             // batch
  const int d0 = (bid & 255) * 16;    // 16 channels per block
  const int tid = threadIdx.x;
  const int n = tid & 15;
  const int dc = tid >> 4;
  const int d = d0 + dc;

  const float A = -expf(A_log[d * DS + n]);
  const float Dd = Dvec[d];

  // loader mapping: thread tid -> row lt (0..63), 4-element slice lf
  const int lt = tid >> 2;
  const int lf = (tid & 3) * 4;
  const int rowbase = b * SEQLEN;

  float4 rdt, rx, rB, rC;
  {
    const int row = rowbase + lt;
    rdt = *(const float4*)&dtbuf[row * DI + d0 + lf];
    rx  = *(const float4*)&x[row * DI + d0 + lf];
    rB  = *(const float4*)&xp[row * RTOT + RDT + lf];
    rC  = *(const float4*)&xp[row * RTOT + RDT + DS + lf];
  }

  float h = 0.f;

  for (int c = 0; c < NCH; ++c) {
    if (c > 0) __syncthreads();   // prev compute done

    // regs -> transposed LDS tiles (4x ds_write_b64 each, 2-way max = free)
    {
      const float rdta[4] = {rdt.x, rdt.y, rdt.z, rdt.w};
      const float rxa[4]  = {rx.x, rx.y, rx.z, rx.w};
      const float rBa[4]  = {rB.x, rB.y, rB.z, rB.w};
      const float rCa[4]  = {rC.x, rC.y, rC.z, rC.w};
#pragma unroll
      for (int j = 0; j < 4; ++j) {
        dxS[lf + j][lt] = make_float2(rdta[j], rxa[j]);
        bcS[lf + j][lt] = make_float2(rBa[j], rCa[j]);
      }
    }

    // store previous chunk's y (after barrier; different LDS region)
    if (c > 0) {
      const int prow = rowbase + (c - 1) * TC + lt;
      float4 yv = *(const float4*)&yS[lt][lf];
      *(float4*)&out[prow * DI + d0 + lf] = yv;
    }

    __syncthreads();              // tiles ready; yS reads done

    // prefetch next chunk into registers
    if (c < NCH - 1) {
      const int row = rowbase + (c + 1) * TC + lt;
      rdt = *(const float4*)&dtbuf[row * DI + d0 + lf];
      rx  = *(const float4*)&x[row * DI + d0 + lf];
      rB  = *(const float4*)&xp[row * RTOT + RDT + lf];
      rC  = *(const float4*)&xp[row * RTOT + RDT + DS + lf];
    }

    // 64 sequential steps, 2 per b128 read pair
#pragma unroll 8
    for (int t = 0; t < TC; t += 2) {
      const float4 dx2 = *(const float4*)&dxS[dc][t];  // dt0,x0,dt1,x1
      const float4 bc2 = *(const float4*)&bcS[n][t];   // B0,C0,B1,C1
      const float dA0 = __expf(dx2.x * A);
      h = fmaf(dA0, h, dx2.x * dx2.y * bc2.x);
      const float p0 = row16_reduce_add(h * bc2.y);
      if (n == 15) yS[t][dc] = fmaf(Dd, dx2.y, p0);
      const float dA1 = __expf(dx2.z * A);
      h = fmaf(dA1, h, dx2.z * dx2.w * bc2.z);
      const float p1 = row16_reduce_add(h * bc2.w);
      if (n == 15) yS[t + 1][dc] = fmaf(Dd, dx2.w, p1);
    }
  }

  __syncthreads();
  {
    const int prow = rowbase + (NCH - 1) * TC + lt;
    float4 yv = *(const float4*)&yS[lt][lf];
    *(float4*)&out[prow * DI + d0 + lf] = yv;
  }
}

// ---------------------------------------------------------------------------
extern "C" void kernel_launch(void* const* d_in, const int* in_sizes, int n_in,
                              void* d_out, int out_size, void* d_ws, size_t ws_size,
                              hipStream_t stream) {
  const float* x     = (const float*)d_in[0];  // (2,512,4096)
  const float* A_log = (const float*)d_in[1];  // (4096,16)
  const float* Dv    = (const float*)d_in[2];  // (4096,)
  const float* W     = (const float*)d_in[3];  // (160,4096)
  const float* dtw   = (const float*)d_in[4];  // (4096,128)
  const float* dtb   = (const float*)d_in[5];  // (4096,)
  float* out = (float*)d_out;

  // Workspace layout (part aliases dtbuf: part is dead before gemm_dt writes)
  char* ws = (char*)d_ws;
  float* dtbuf = (float*)ws;                         // 16,777,216 B
  float* part  = (float*)ws;                         // 10,485,760 B (aliased)
  float* xp    = (float*)(ws + 16777216);            //    655,360 B
  bf16*  Wb    = (bf16*)(ws + 16777216 + 655360);    //  1,310,720 B
  bf16*  dtwb  = (bf16*)(ws + 16777216 + 655360 + 1310720);            // 1,048,576 B
  bf16*  dtinb = (bf16*)(ws + 16777216 + 655360 + 1310720 + 1048576);  //   262,144 B
  // total ~20.05 MB

  cast_bf16<<<dim3(640), 256, 0, stream>>>(W, Wb, RTOT * DI / 4);
  cast_bf16<<<dim3(512), 256, 0, stream>>>(dtw, dtwb, DI * RDT / 4);
  gemm_xp_mfma<<<dim3(16, KSPLIT), 256, 0, stream>>>(x, Wb, part);
  reduce_xp<<<dim3(640), 256, 0, stream>>>(part, xp, dtinb);
  gemm_dt_mfma<<<dim3(16, 32), 256, 0, stream>>>(dtinb, dtwb, dtb, dtbuf);
  scan_kernel<<<dim3(512), 256, 0, stream>>>(x, A_log, Dv, xp, dtbuf, out);
}

// Round 4
// 135.961 us; speedup vs baseline: 2.9401x; 1.2187x over previous
//
#include <hip/hip_runtime.h>
#include <math.h>

// Problem constants (SelectiveSSM)
#define BATCH   2
#define SEQLEN  512
#define DI      4096      // d_inner
#define DS      16        // d_state
#define RDT     128       // dt_rank
#define RTOT    160       // dt_rank + 2*d_state
#define BL      1024      // BATCH*SEQLEN rows

#define KSPLIT  32        // GEMM1 k-split: 4096/32 = 128 per block
#define KSL     (DI / KSPLIT)

typedef __bf16 bf16;
typedef bf16  bf16x8 __attribute__((ext_vector_type(8)));
typedef bf16  bf16x4 __attribute__((ext_vector_type(4)));
typedef float f32x4  __attribute__((ext_vector_type(4)));

// ---------------------------------------------------------------------------
// Cast W and dtw to bf16 in one launch. Grid covers both arrays exactly:
// (160*4096 + 4096*128)/4 = 294912 threads = 1152 blocks.
// ---------------------------------------------------------------------------
__global__ __launch_bounds__(256) void cast_both(const float* __restrict__ W,
                                                 const float* __restrict__ dtw,
                                                 bf16* __restrict__ Wb,
                                                 bf16* __restrict__ dtwb) {
  const int i = blockIdx.x * 256 + threadIdx.x;
  const float4* src;
  bf16* dst;
  int j;
  if (i < RTOT * DI / 4) { src = (const float4*)W;   dst = Wb;   j = i; }
  else                   { src = (const float4*)dtw; dst = dtwb; j = i - RTOT * DI / 4; }
  float4 v = src[j];
  bf16x4 o;
  o[0] = (bf16)v.x; o[1] = (bf16)v.y; o[2] = (bf16)v.z; o[3] = (bf16)v.w;
  *(bf16x4*)(dst + 4 * (size_t)j) = o;
}

// ---------------------------------------------------------------------------
// GEMM1 (MFMA, no LDS): part[ks][row][r] = sum_{k in slice} x[row,k]*W[r,k]
// grid (16 M-tiles, 32 k-splits) = 512 blocks -> 2 blocks/CU, 2 waves/SIMD.
// ---------------------------------------------------------------------------
__global__ __launch_bounds__(256) void gemm_xp_mfma(const float* __restrict__ x,
                                                    const bf16* __restrict__ Wb,
                                                    float* __restrict__ part) {
  const int tid = threadIdx.x;
  const int w = tid >> 6;
  const int lane = tid & 63;
  const int m = lane & 15;
  const int q = lane >> 4;
  const int row0 = blockIdx.x * 64 + 16 * w;
  const int k0 = blockIdx.y * KSL;             // 128-wide K slice

  f32x4 acc[10] = {};

  const float* ap = x + (size_t)(row0 + m) * DI + k0 + 8 * q;
  const bf16*  bp = Wb + (size_t)m * DI + k0 + 8 * q;

#pragma unroll
  for (int kk = 0; kk < KSL; kk += 32) {
    float4 a0 = *(const float4*)(ap + kk);
    float4 a1 = *(const float4*)(ap + kk + 4);
    bf16x8 af;
    af[0] = (bf16)a0.x; af[1] = (bf16)a0.y; af[2] = (bf16)a0.z; af[3] = (bf16)a0.w;
    af[4] = (bf16)a1.x; af[5] = (bf16)a1.y; af[6] = (bf16)a1.z; af[7] = (bf16)a1.w;
#pragma unroll
    for (int nt = 0; nt < 10; ++nt) {
      bf16x8 bfv = *(const bf16x8*)(bp + (size_t)nt * 16 * DI + kk);
      acc[nt] = __builtin_amdgcn_mfma_f32_16x16x32_bf16(af, bfv, acc[nt], 0, 0, 0);
    }
  }

  // C/D layout: col = m (N dim), row = 4q + r (M dim)
  float* p = part + (size_t)blockIdx.y * (BL * RTOT);
#pragma unroll
  for (int nt = 0; nt < 10; ++nt)
#pragma unroll
    for (int r = 0; r < 4; ++r)
      p[(size_t)(row0 + 4 * q + r) * RTOT + nt * 16 + m] = acc[nt][r];
}

// ---------------------------------------------------------------------------
// Reduce k-splits -> compact outputs:
//   cols 0..127  -> dtin bf16 [1024][128]   (GEMM2-in-scan A operand)
//   cols 128..159-> BCf fp32  [1024][32]    (scan B,C; B=0..15, C=16..31)
// grid 160 x 256; each thread reduces 4 consecutive outputs (same row).
// ---------------------------------------------------------------------------
__global__ __launch_bounds__(256) void reduce_xp(const float* __restrict__ part,
                                                 float* __restrict__ BCf,
                                                 bf16* __restrict__ dtinb) {
  const int o = (blockIdx.x * 256 + threadIdx.x) * 4;
  float4 s = make_float4(0.f, 0.f, 0.f, 0.f);
#pragma unroll
  for (int k = 0; k < KSPLIT; ++k) {
    float4 v = *(const float4*)&part[(size_t)k * (BL * RTOT) + o];
    s.x += v.x; s.y += v.y; s.z += v.z; s.w += v.w;
  }
  const int row = o / RTOT;
  const int col = o - row * RTOT;   // multiple of 4; group never straddles rows
  if (col < RDT) {
    bf16x4 ob;
    ob[0] = (bf16)s.x; ob[1] = (bf16)s.y; ob[2] = (bf16)s.z; ob[3] = (bf16)s.w;
    *(bf16x4*)(dtinb + (size_t)row * RDT + col) = ob;
  } else {
    *(float4*)&BCf[(size_t)row * 32 + (col - RDT)] = s;
  }
}

// ---------------------------------------------------------------------------
// 16-lane (DPP row) sum reduction on the VALU pipe. Result valid in lane 15
// of each 16-lane row.
// ---------------------------------------------------------------------------
__device__ __forceinline__ float row16_reduce_add(float p) {
  p += __int_as_float(__builtin_amdgcn_update_dpp(
      0, __float_as_int(p), 0x111, 0xf, 0xf, true));  // row_shr:1
  p += __int_as_float(__builtin_amdgcn_update_dpp(
      0, __float_as_int(p), 0x112, 0xf, 0xf, true));  // row_shr:2
  p += __int_as_float(__builtin_amdgcn_update_dpp(
      0, __float_as_int(p), 0x114, 0xf, 0xf, true));  // row_shr:4
  p += __int_as_float(__builtin_amdgcn_update_dpp(
      0, __float_as_int(p), 0x118, 0xf, 0xf, true));  // row_shr:8
  return p;
}

// ---------------------------------------------------------------------------
// Fused GEMM2 + selective scan.
// Block = one batch x 16 channels (512 blocks x 256 threads).
// Per 64-t chunk: dt computed in-block via MFMA (dtin x dtw^T + bias,
// softplus) into dtS; x/B/C staged via coalesced float4 -> LDS transpose;
// then 64 sequential steps in 8 explicit register-batched groups of 8.
// ---------------------------------------------------------------------------
#define TC  64
#define TCP 68
#define NCH (SEQLEN / TC)

__global__ __launch_bounds__(256) void scan_fused(const float* __restrict__ x,
                                                  const float* __restrict__ A_log,
                                                  const float* __restrict__ Dvec,
                                                  const float* __restrict__ BCf,
                                                  const bf16* __restrict__ dtin,
                                                  const bf16* __restrict__ dtwb,
                                                  const float* __restrict__ dtb,
                                                  float* __restrict__ out) {
  __shared__ __align__(16) float dtS[16][TCP];  // [dc][t]
  __shared__ __align__(16) float xS[16][TCP];   // [dc][t]
  __shared__ __align__(16) float BS[16][TCP];   // [n][t]
  __shared__ __align__(16) float CS[16][TCP];   // [n][t]
  __shared__ __align__(16) float yS[TC][16];    // [t][dc]

  const int bid = blockIdx.x;         // 0..511
  const int b = bid >> 8;
  const int d0 = (bid & 255) * 16;
  const int tid = threadIdx.x;
  const int n = tid & 15;             // state (scan) / MFMA m
  const int dc = tid >> 4;            // channel (scan)
  const int d = d0 + dc;
  const int w = tid >> 6;             // wave id (MFMA staging)
  const int m = tid & 15;
  const int q = (tid >> 4) & 3;

  const float A = -expf(A_log[d * DS + n]);
  const float Dd = Dvec[d];
  const float bias = dtb[d0 + m];

  // dtw B-fragments: chunk-invariant, held in registers
  bf16x8 bfragW[4];
#pragma unroll
  for (int k = 0; k < 4; ++k)
    bfragW[k] = *(const bf16x8*)(dtwb + (size_t)(d0 + m) * RDT + 32 * k + 8 * q);

  // loader mapping for x/B/C/y: thread -> row lt (0..63), 4-elem slice lf
  const int lt = tid >> 2;
  const int lf = (tid & 3) * 4;
  const int rowbase = b * SEQLEN;

  // prefetch chunk 0
  bf16x8 afrag[4];
  float4 rx, rB, rC;
  {
    const int arow = rowbase + 16 * w + m;
#pragma unroll
    for (int k = 0; k < 4; ++k)
      afrag[k] = *(const bf16x8*)(dtin + (size_t)arow * RDT + 32 * k + 8 * q);
    const int row = rowbase + lt;
    rx = *(const float4*)&x[(size_t)row * DI + d0 + lf];
    rB = *(const float4*)&BCf[row * 32 + lf];
    rC = *(const float4*)&BCf[row * 32 + 16 + lf];
  }

  float h = 0.f;

  for (int c = 0; c < NCH; ++c) {
    if (c > 0) __syncthreads();   // prev compute (LDS reads + yS writes) done

    // ---- stage dt via MFMA + softplus ----
    {
      f32x4 acc = {};
#pragma unroll
      for (int k = 0; k < 4; ++k)
        acc = __builtin_amdgcn_mfma_f32_16x16x32_bf16(afrag[k], bfragW[k], acc, 0, 0, 0);
      // D layout: col m = channel, row 4q+r = timestep within 16-row tile
#pragma unroll
      for (int r = 0; r < 4; ++r) {
        const float z = acc[r] + bias;
        dtS[m][16 * w + 4 * q + r] = (z > 20.f) ? z : __logf(1.f + __expf(z));
      }
    }
    // ---- stage x, B, C (transposed) ----
    {
      const float rxa[4] = {rx.x, rx.y, rx.z, rx.w};
      const float rBa[4] = {rB.x, rB.y, rB.z, rB.w};
      const float rCa[4] = {rC.x, rC.y, rC.z, rC.w};
#pragma unroll
      for (int j = 0; j < 4; ++j) {
        xS[lf + j][lt] = rxa[j];
        BS[lf + j][lt] = rBa[j];
        CS[lf + j][lt] = rCa[j];
      }
    }
    // ---- store previous chunk's y (different LDS region; reads pre-barrier2)
    if (c > 0) {
      const int prow = rowbase + (c - 1) * TC + lt;
      float4 yv = *(const float4*)&yS[lt][lf];
      *(float4*)&out[(size_t)prow * DI + d0 + lf] = yv;
    }

    __syncthreads();              // tiles ready; yS reads done

    // ---- prefetch next chunk ----
    if (c < NCH - 1) {
      const int arow = rowbase + (c + 1) * TC + 16 * w + m;
#pragma unroll
      for (int k = 0; k < 4; ++k)
        afrag[k] = *(const bf16x8*)(dtin + (size_t)arow * RDT + 32 * k + 8 * q);
      const int row = rowbase + (c + 1) * TC + lt;
      rx = *(const float4*)&x[(size_t)row * DI + d0 + lf];
      rB = *(const float4*)&BCf[row * 32 + lf];
      rC = *(const float4*)&BCf[row * 32 + 16 + lf];
    }

    // ---- 64 steps: 8 groups of 8, explicit register batches ----
    for (int g = 0; g < 8; ++g) {
      const int t0 = 8 * g;
      const float4 dv0 = *(const float4*)&dtS[dc][t0];
      const float4 dv1 = *(const float4*)&dtS[dc][t0 + 4];
      const float4 xv0 = *(const float4*)&xS[dc][t0];
      const float4 xv1 = *(const float4*)&xS[dc][t0 + 4];
      const float4 Bv0 = *(const float4*)&BS[n][t0];
      const float4 Bv1 = *(const float4*)&BS[n][t0 + 4];
      const float4 Cv0 = *(const float4*)&CS[n][t0];
      const float4 Cv1 = *(const float4*)&CS[n][t0 + 4];
      const float dt[8] = {dv0.x, dv0.y, dv0.z, dv0.w, dv1.x, dv1.y, dv1.z, dv1.w};
      const float xv[8] = {xv0.x, xv0.y, xv0.z, xv0.w, xv1.x, xv1.y, xv1.z, xv1.w};
      const float Bv[8] = {Bv0.x, Bv0.y, Bv0.z, Bv0.w, Bv1.x, Bv1.y, Bv1.z, Bv1.w};
      const float Cv[8] = {Cv0.x, Cv0.y, Cv0.z, Cv0.w, Cv1.x, Cv1.y, Cv1.z, Cv1.w};

      float e[8], u[8], p[8];
#pragma unroll
      for (int j = 0; j < 8; ++j) {       // independent: pipelines freely
        e[j] = __expf(dt[j] * A);
        u[j] = dt[j] * xv[j] * Bv[j];
      }
#pragma unroll
      for (int j = 0; j < 8; ++j) {       // the only true serial chain
        h = fmaf(e[j], h, u[j]);
        p[j] = h * Cv[j];
      }
#pragma unroll
      for (int j = 0; j < 8; ++j)         // 8 independent DPP chains
        p[j] = row16_reduce_add(p[j]);
      if (n == 15) {
#pragma unroll
        for (int j = 0; j < 8; ++j)
          yS[t0 + j][dc] = fmaf(Dd, xv[j], p[j]);
      }
    }
  }

  __syncthreads();
  {
    const int prow = rowbase + (NCH - 1) * TC + lt;
    float4 yv = *(const float4*)&yS[lt][lf];
    *(float4*)&out[(size_t)prow * DI + d0 + lf] = yv;
  }
}

// ---------------------------------------------------------------------------
extern "C" void kernel_launch(void* const* d_in, const int* in_sizes, int n_in,
                              void* d_out, int out_size, void* d_ws, size_t ws_size,
                              hipStream_t stream) {
  const float* x     = (const float*)d_in[0];  // (2,512,4096)
  const float* A_log = (const float*)d_in[1];  // (4096,16)
  const float* Dv    = (const float*)d_in[2];  // (4096,)
  const float* W     = (const float*)d_in[3];  // (160,4096)
  const float* dtw   = (const float*)d_in[4];  // (4096,128)
  const float* dtb   = (const float*)d_in[5];  // (4096,)
  float* out = (float*)d_out;

  // Workspace layout (~23.7 MB)
  char* ws = (char*)d_ws;
  float* part  = (float*)ws;                       // 32*1024*160*4 = 20,971,520 B
  bf16*  Wb    = (bf16*)(ws + 20971520);           //  1,310,720 B
  bf16*  dtwb  = (bf16*)(ws + 22282240);           //  1,048,576 B
  float* BCf   = (float*)(ws + 23330816);          //    131,072 B
  bf16*  dtinb = (bf16*)(ws + 23461888);           //    262,144 B

  cast_both<<<dim3(1152), 256, 0, stream>>>(W, dtw, Wb, dtwb);
  gemm_xp_mfma<<<dim3(16, KSPLIT), 256, 0, stream>>>(x, Wb, part);
  reduce_xp<<<dim3(160), 256, 0, stream>>>(part, BCf, dtinb);
  scan_fused<<<dim3(512), 256, 0, stream>>>(x, A_log, Dv, BCf, dtinb, dtwb, dtb, out);
}